// Round 1
// baseline (410.502 us; speedup 1.0000x reference)
//
#include <hip/hip_runtime.h>
#include <cstdint>
#include <cstddef>

// ---------------------------------------------------------------------------
// DifferentialAttention on MI355X (gfx950), bf16 MFMA pipeline.
// B=2 T=2048 D=2048 H=16 HD=128 HHD=64  SCALE=1/8
// R7: fused-QKV GEMM rebuilt as the 256^2 8-phase template (T1+T2+T3/T4+T5):
//   - 512 threads (8 waves 2Mx4N), BM=BN=256, BK=64, per-wave 128x64 out.
//   - LDS half-tile rings: A 5x16KB, B 4x16KB = 144KB, st_16x32 swizzle
//     (applied on the pre-swizzled global source; global_load_lds stays
//     linear; reads XOR the same involution).
//   - counted s_waitcnt vmcnt(2) once per K-tile (never 0 in steady state);
//     raw s_barrier (no vmcnt(0) drain) + setprio(1) around MFMA cluster.
//   - XCD-aware block swizzle: each XCD owns a 3-ntile column band (B panels
//     L2-resident), mt-major within.
// Out-proj GEMM / attention / transposes unchanged from R6.
// ---------------------------------------------------------------------------

typedef unsigned short u16;
typedef __bf16 bf16x8 __attribute__((ext_vector_type(8)));
typedef float f32x4 __attribute__((ext_vector_type(4)));

#define LOG2E 1.44269504088896340736f
// p = exp(s*0.125 - 8) = exp2(s * KS - CB); fixed bias 8 replaces running max
#define KS 0.18033688011112042f   /* 0.125 * log2(e) */
#define CB 11.541560327111707f    /* 8.0  * log2(e) */

__device__ __forceinline__ u16 f2bu(float f) {
  unsigned int x = __float_as_uint(f);
  x += 0x7fffu + ((x >> 16) & 1u);   // round-to-nearest-even (finite inputs)
  return (u16)(x >> 16);
}

// global -> LDS staging, 16B per lane. lds_uniform must be wave-uniform;
// hardware places lane's data at lds_uniform + lane*16.
__device__ __forceinline__ void stage16(const void* g, void* lds_uniform, int lane) {
#if defined(__has_builtin) && __has_builtin(__builtin_amdgcn_global_load_lds)
  (void)lane;
  __builtin_amdgcn_global_load_lds(
      (__attribute__((address_space(1))) void*)(g),
      (__attribute__((address_space(3))) void*)(lds_uniform), 16, 0, 0);
#else
  *(uint4*)((char*)lds_uniform + lane * 16) = *(const uint4*)g;
#endif
}

// ---------------------------------------------------------------------------
// fp32 -> bf16 elementwise (vectorized), exact-grid
// ---------------------------------------------------------------------------
__global__ void f32_to_bf16_k(const float* __restrict__ in, u16* __restrict__ out, int n4) {
  int i = blockIdx.x * blockDim.x + threadIdx.x;
  if (i < n4) {
    float4 v = ((const float4*)in)[i];
    ushort4 u;
    u.x = f2bu(v.x); u.y = f2bu(v.y); u.z = f2bu(v.z); u.w = f2bu(v.w);
    ((ushort4*)out)[i] = u;
  }
}

// ---------------------------------------------------------------------------
// fp32 (R x C) -> bf16 transposed (C x R), 32x32 LDS tiles
// ---------------------------------------------------------------------------
__global__ void transpose_f32_bf16(const float* __restrict__ in, u16* __restrict__ out,
                                   int R, int C) {
  __shared__ u16 tile[32][33];
  const int tx = threadIdx.x & 31, ty = threadIdx.x >> 5; // 32 x 8
  const int c0 = blockIdx.x * 32, r0 = blockIdx.y * 32;
#pragma unroll
  for (int i = 0; i < 32; i += 8)
    tile[ty + i][tx] = f2bu(in[(size_t)(r0 + ty + i) * C + c0 + tx]);
  __syncthreads();
#pragma unroll
  for (int i = 0; i < 32; i += 8)
    out[(size_t)(c0 + ty + i) * R + r0 + tx] = tile[tx][ty + i];
}

// ---------------------------------------------------------------------------
// Legacy 128x128 GEMM (m97-structure) — used for out-proj and fallback path.
// C(M,N) = A(M,K) @ BT(N,K)^T   all bf16 in, fp32 accumulate.
// MODE 0: bf16 natural   MODE 1: fp32 natural
// MODE 2: bf16 V-transpose -> out[((b*16+h)*128+d)*2048 + t]
// ---------------------------------------------------------------------------
template <int MODE>
__global__ void gemm_bt(const u16* __restrict__ A, const u16* __restrict__ BT,
                        void* __restrict__ C, u16* __restrict__ C2,
                        int Mdim, int Ndim, int Kdim) {
  __shared__ __align__(16) u16 As[128 * 32];
  __shared__ __align__(16) u16 Bs[128 * 32];
  const int tid = threadIdx.x;
  const int lane = tid & 63;
  const int w = tid >> 6;
  const int wm = w & 1, wn = w >> 1;
  const int li = lane & 15, lh = lane >> 4;
  const int m0 = blockIdx.x * 128;
  const int n0 = blockIdx.y * 128;

  const f32x4 fzero = {0.f, 0.f, 0.f, 0.f};
  f32x4 acc[4][4];
#pragma unroll
  for (int i = 0; i < 4; ++i)
#pragma unroll
    for (int jj = 0; jj < 4; ++jj) acc[i][jj] = fzero;

  for (int k0 = 0; k0 < Kdim; k0 += 32) {
#pragma unroll
    for (int i = 0; i < 2; ++i) {
      const int c = i * 256 + w * 64 + lane;
      stage16(A + (size_t)(m0 + (c >> 2)) * Kdim + k0 + ((c & 3) << 3),
              (char*)As + (size_t)(i * 256 + w * 64) * 16, lane);
      stage16(BT + (size_t)(n0 + (c >> 2)) * Kdim + k0 + ((c & 3) << 3),
              (char*)Bs + (size_t)(i * 256 + w * 64) * 16, lane);
    }
    __syncthreads();

    bf16x8 af[4], bfr[4];
#pragma unroll
    for (int mt = 0; mt < 4; ++mt)
      af[mt] = *(const bf16x8*)&As[(wm * 64 + mt * 16 + li) * 32 + lh * 8];
#pragma unroll
    for (int nt = 0; nt < 4; ++nt)
      bfr[nt] = *(const bf16x8*)&Bs[(wn * 64 + nt * 16 + li) * 32 + lh * 8];
#pragma unroll
    for (int mt = 0; mt < 4; ++mt)
#pragma unroll
      for (int nt = 0; nt < 4; ++nt)
        acc[mt][nt] = __builtin_amdgcn_mfma_f32_16x16x32_bf16(af[mt], bfr[nt], acc[mt][nt], 0, 0, 0);
    __syncthreads();
  }

  // epilogue: C/D layout col = lane&15, row = (lane>>4)*4 + reg
#pragma unroll
  for (int mt = 0; mt < 4; ++mt) {
#pragma unroll
    for (int nt = 0; nt < 4; ++nt) {
      const int mb = m0 + wm * 64 + mt * 16 + lh * 4; // 4 consecutive rows
      const int n = n0 + wn * 64 + nt * 16 + li;
      if (MODE == 0) {
        u16* o = (u16*)C;
#pragma unroll
        for (int r = 0; r < 4; ++r)
          o[(size_t)(mb + r) * Ndim + n] = f2bu(acc[mt][nt][r]);
      } else if (MODE == 1) {
        float* o = (float*)C;
#pragma unroll
        for (int r = 0; r < 4; ++r)
          o[(size_t)(mb + r) * Ndim + n] = acc[mt][nt][r];
      } else {
        u16* o = (u16*)C;
        const int bb = mb >> 11, t = mb & 2047;
        const int hh = n >> 7, d = n & 127;
        ushort4 u;
        u.x = f2bu(acc[mt][nt][0]);
        u.y = f2bu(acc[mt][nt][1]);
        u.z = f2bu(acc[mt][nt][2]);
        u.w = f2bu(acc[mt][nt][3]);
        *(ushort4*)&o[((size_t)((bb * 16 + hh) * 128 + d) << 11) + t] = u;
      }
    }
  }
}

// ---------------------------------------------------------------------------
// 256x256 8-phase fused-QKV GEMM.  A(M,K) @ BT(N,K)^T, M=4096 N=6144 K=2048.
// N-chunk [0,2048) -> Q bf16 into C; [2048,4096) -> K bf16 into C+4096*2048;
// [4096,6144) -> V per-head transposed into C2.
//
// LDS: half-tile = 128 rows x 64 k bf16 = 16KB, stored as [2 ks][128][32]
// (64B rows) with st_16x32 swizzle: byte ^= ((byte>>9)&1)<<5, i.e. u16 idx
// ^= ((row>>3)&1)<<4.  global_load_lds writes LINEAR; the global source is
// pre-swizzled (involution), reads apply the same XOR.
// Rings: A slots = half g%5, B slots = g%4 (g = 2*kt + half).
// Per K-tile (4 phases), issue schedule:
//   P0: A(2kt+3)   P1: B(2kt+2)   P2: B(2kt+3)   P3: A(2kt+4)
// then s_waitcnt vmcnt(2) (leaves only A(2kt+4) in flight) + barrier.
// Slot-reuse safety: every stage targets a slot whose previous occupant was
// last read in tile kt-1; all waves passed the tile-kt P0 barrier by then.
// Tail: for kt >= NT-2 the trailing A prefetch is guarded off -> vmcnt(0).
// ---------------------------------------------------------------------------
__device__ __forceinline__ void stage_half256(const u16* __restrict__ gbase, int Kdim,
                                              u16* lds_slot, int tid) {
#pragma unroll
  for (int j = 0; j < 2; ++j) {
    const int c = j * 512 + tid;                 // 0..1023, 16B chunk id
    const int ks = c >> 9;                       // k-slice (0..1)
    const int o = (c & 511) << 4;                // byte offset in 8KB block
    const int osz = o ^ (((o >> 9) & 1) << 5);   // involutive st_16x32 swizzle
    const int row = osz >> 6;                    // 0..127
    const int kel = (osz & 63) >> 1;             // element in 32-slice {0,8,16,24}
    stage16(gbase + (size_t)row * Kdim + ks * 32 + kel,
            (char*)lds_slot + ((size_t)(j * 512 + (tid & ~63)) << 4), tid & 63);
  }
}

#define PHASE256(MH, KS, LOADB, STAGESTMT, TAILSTMT)                           \
  {                                                                            \
    bf16x8 af[4];                                                              \
    _Pragma("unroll")                                                          \
    for (int mq = 0; mq < 4; ++mq)                                             \
      af[mq] = *(const bf16x8*)&As[sA][KS][((MH)*4 + mq) * 16 + li][lhx8];     \
    if (LOADB) {                                                               \
      _Pragma("unroll")                                                        \
      for (int nt = 0; nt < 4; ++nt)                                           \
        bfc[nt] = *(const bf16x8*)&Bs[sB][KS][brow + nt * 16 + li][lhx8];      \
    }                                                                          \
    STAGESTMT;                                                                 \
    __builtin_amdgcn_s_barrier();                                              \
    asm volatile("" ::: "memory");                                             \
    __builtin_amdgcn_s_setprio(1);                                             \
    _Pragma("unroll")                                                          \
    for (int mq = 0; mq < 4; ++mq) {                                           \
      _Pragma("unroll")                                                        \
      for (int nt = 0; nt < 4; ++nt)                                           \
        acc[(MH)*4 + mq][nt] = __builtin_amdgcn_mfma_f32_16x16x32_bf16(        \
            af[mq], bfc[nt], acc[(MH)*4 + mq][nt], 0, 0, 0);                   \
    }                                                                          \
    __builtin_amdgcn_s_setprio(0);                                             \
    TAILSTMT;                                                                  \
    __builtin_amdgcn_s_barrier();                                              \
    asm volatile("" ::: "memory");                                             \
  }

__global__ __launch_bounds__(512, 2)
void gemm256_qkv(const u16* __restrict__ A, const u16* __restrict__ BT,
                 u16* __restrict__ C, u16* __restrict__ C2, int Kdim) {
  __shared__ __align__(16) u16 As[5][2][128][32];   // 80KB, A half-tile ring
  __shared__ __align__(16) u16 Bs[4][2][128][32];   // 64KB, B half-tile ring

  const int tid = threadIdx.x;
  const int lane = tid & 63;
  const int w = tid >> 6;              // 0..7
  const int wm = w >> 2;               // M-half of the block (128 rows)
  const int wn = w & 3;                // N quarter (64 cols)
  const int li = lane & 15, lh = lane >> 4;
  const int lhx8 = (lh ^ (((li >> 3) & 1) << 1)) * 8;   // swizzled k-chunk
  const int brow = (wn & 1) * 64;      // row base inside B half-tile

  // XCD-aware swizzle: xcd owns ntiles [3*xcd, 3*xcd+2], mt-major inside.
  const int bid = blockIdx.x;          // 0..383
  const int xcd = bid & 7;
  const int local = bid >> 3;          // 0..47
  const int mtile = local / 3;
  const int ntile = xcd * 3 + (local % 3);
  const int m0 = mtile * 256, n0 = ntile * 256;

  const int NT = Kdim >> 6;            // K-tiles of 64
  const u16* Abase = A + (size_t)m0 * Kdim;
  const u16* Bbase = BT + (size_t)n0 * Kdim;

  auto stA = [&](int g) {
    if (g < 2 * NT)
      stage_half256(Abase + (size_t)((g & 1) * 128) * Kdim + (g >> 1) * 64, Kdim,
                    &As[g % 5][0][0][0], tid);
  };
  auto stB = [&](int g) {
    if (g < 2 * NT)
      stage_half256(Bbase + (size_t)((g & 1) * 128) * Kdim + (g >> 1) * 64, Kdim,
                    &Bs[g & 3][0][0][0], tid);
  };

  const f32x4 fzero = {0.f, 0.f, 0.f, 0.f};
  f32x4 acc[8][4];
#pragma unroll
  for (int i = 0; i < 8; ++i)
#pragma unroll
    for (int jj = 0; jj < 4; ++jj) acc[i][jj] = fzero;

  // prologue: everything the steady-state stream never issues.
  stA(0); stB(0); stA(1); stB(1); stA(2);
  asm volatile("s_waitcnt vmcnt(2)" ::: "memory");   // A0,B0,A1,B1 landed
  __builtin_amdgcn_s_barrier();
  asm volatile("" ::: "memory");

  bf16x8 bfc[4];
  for (int kt = 0; kt < NT; ++kt) {
    const int sA = (2 * kt + wm) % 5;
    const int sB = (2 * kt + (wn >> 1)) & 3;
    PHASE256(0, 0, 1, stA(2 * kt + 3), ((void)0));
    PHASE256(1, 0, 0, stB(2 * kt + 2), ((void)0));
    PHASE256(0, 1, 1, stB(2 * kt + 3), ((void)0));
    PHASE256(1, 1, 0, stA(2 * kt + 4),
             if (kt + 2 < NT) { asm volatile("s_waitcnt vmcnt(2)" ::: "memory"); }
             else             { asm volatile("s_waitcnt vmcnt(0)" ::: "memory"); });
  }

  // epilogue: C/D layout col = lane&15, row = (lane>>4)*4 + reg
  const int proj = n0 >> 11;                 // 0=Q, 1=K, 2=V (block-uniform)
  const int nB = (n0 & 2047) + wn * 64;
  const int mB = m0 + wm * 128;
#pragma unroll
  for (int mt = 0; mt < 8; ++mt) {
#pragma unroll
    for (int nt = 0; nt < 4; ++nt) {
      const int mb = mB + mt * 16 + lh * 4;  // 4 consecutive rows
      const int n = nB + nt * 16 + li;
      if (proj < 2) {
        u16* o = C + (size_t)proj * 4096 * 2048;
#pragma unroll
        for (int r = 0; r < 4; ++r)
          o[(size_t)(mb + r) * 2048 + n] = f2bu(acc[mt][nt][r]);
      } else {
        const int bb = mb >> 11, t = mb & 2047;
        const int hh = n >> 7, d = n & 127;
        ushort4 u;
        u.x = f2bu(acc[mt][nt][0]);
        u.y = f2bu(acc[mt][nt][1]);
        u.z = f2bu(acc[mt][nt][2]);
        u.w = f2bu(acc[mt][nt][3]);
        *(ushort4*)&C2[((size_t)((bb * 16 + hh) * 128 + d) << 11) + t] = u;
      }
    }
  }
}

// ---------------------------------------------------------------------------
// Flash differential attention: paired q-tiles, double-buffered DMA.
// grid = 512 (1D): bh = idx&31 (XCD pin), pair = idx>>5 in [0,16).
// Block processes q-tile `pair` then q-tile `31-pair` -> 33 iters uniform.
// Per iter: one barrier; prefetch K/V(j+1) into alt buffer right after it.
// Wave w owns Q rows t0+w*16..+15; P round-trip is wave-private (no barrier).
// Fixed-bias softmax; l reduced once per phase. LDS 80KB -> 2 blocks/CU.
// ---------------------------------------------------------------------------
__device__ __forceinline__ void stage_kv(const u16* __restrict__ kbase,
                                         const u16* __restrict__ vbase, int j,
                                         u16* ksBuf, u16* vsBuf, int w, int lane) {
  const int kst_r = lane >> 4, kst_c = lane & 15;
  const int vst_r = lane >> 3, vst_c = lane & 7;
#pragma unroll
  for (int i = 0; i < 4; ++i) {
    const int t = w * 4 + i;
    const int srow = t * 4 + kst_r;
    const int scb = kst_c ^ (srow & 7);
    stage16(kbase + (size_t)(j * 64 + srow) * 2048 + scb * 8,
            (char*)ksBuf + t * 1024, lane);
    const int drow = t * 8 + vst_r;
    const int dcb = vst_c ^ (drow & 7);
    stage16(vbase + (size_t)drow * 2048 + j * 64 + dcb * 8,
            (char*)vsBuf + t * 1024, lane);
  }
}

__global__ __launch_bounds__(256, 2)
void diff_attn(const u16* __restrict__ Q, const u16* __restrict__ K,
               const u16* __restrict__ VT, const float* __restrict__ lamin,
               u16* __restrict__ AO) {
  __shared__ __align__(16) u16 Ks[2][64 * 128];   // [s][c], col-block swizzled
  __shared__ __align__(16) u16 Vs[2][128 * 64];   // [d][s], col-block swizzled
  __shared__ __align__(16) u16 Ps1[64 * 64];
  __shared__ __align__(16) u16 Ps2[64 * 64];

  const int tid = threadIdx.x, lane = tid & 63, w = tid >> 6;
  const int li = lane & 15, lh = lane >> 4;
  const int bh = blockIdx.x & 31, pair = blockIdx.x >> 5;
  const int b = bh >> 4, h = bh & 15;

  const float lam = 1.f / (1.f + exp2f(-lamin[h] * LOG2E));
  const u16* kbase = K + ((size_t)(b * 2048)) * 2048 + h * 128;  // + s*2048 + c
  const u16* vbase = VT + ((size_t)(b * 16 + h) << 18);          // + d*2048 + s
  const f32x4 fzero = {0.f, 0.f, 0.f, 0.f};

  for (int phase = 0; phase < 2; ++phase) {
    const int it = phase ? 31 - pair : pair;
    const int t0 = it * 64;

    // Q fragments: kk=0,1 -> first 64 dims (S1), kk=2,3 -> second 64 (S2)
    bf16x8 qf[4];
    {
      const u16* qp = Q + (size_t)(b * 2048 + t0 + w * 16 + li) * 2048 + h * 128 + lh * 8;
#pragma unroll
      for (int kk = 0; kk < 4; ++kk) qf[kk] = *(const bf16x8*)(qp + kk * 32);
    }

    f32x4 o1[8], o2[8];
#pragma unroll
    for (int i = 0; i < 8; ++i) { o1[i] = fzero; o2[i] = fzero; }
    float l1p[4] = {0.f, 0.f, 0.f, 0.f};
    float l2p[4] = {0.f, 0.f, 0.f, 0.f};

    if (phase) __syncthreads();   // all waves done reading phase-0 buffers
    stage_kv(kbase, vbase, 0, Ks[0], Vs[0], w, lane);

    for (int j = 0; j <= it; ++j) {
      const int cur = j & 1;
      __syncthreads();  // DMA(j)->buf[cur] drained (vmcnt0); prior reads done
      if (j < it)       // prefetch j+1 into alt buffer; drains at NEXT barrier
        stage_kv(kbase, vbase, j + 1, Ks[cur ^ 1], Vs[cur ^ 1], w, lane);

      const u16* __restrict__ ks = Ks[cur];
      const u16* __restrict__ vs = Vs[cur];
      const bool diag = (j == it);

      // ---- per nt: S = Q@K^T chunk, exp, store P to LDS (wave-private) ----
#pragma unroll
      for (int nt = 0; nt < 4; ++nt) {
        const int srow = nt * 16 + li;
        const int sw = li & 7;
        bf16x8 b0 = *(const bf16x8*)&ks[srow * 128 + ((0 + lh) ^ sw) * 8];
        bf16x8 b1 = *(const bf16x8*)&ks[srow * 128 + ((4 + lh) ^ sw) * 8];
        bf16x8 b2 = *(const bf16x8*)&ks[srow * 128 + ((8 + lh) ^ sw) * 8];
        bf16x8 b3 = *(const bf16x8*)&ks[srow * 128 + ((12 + lh) ^ sw) * 8];
        f32x4 s1 = fzero, s2 = fzero;
        s1 = __builtin_amdgcn_mfma_f32_16x16x32_bf16(qf[0], b0, s1, 0, 0, 0);
        s1 = __builtin_amdgcn_mfma_f32_16x16x32_bf16(qf[1], b1, s1, 0, 0, 0);
        s2 = __builtin_amdgcn_mfma_f32_16x16x32_bf16(qf[2], b2, s2, 0, 0, 0);
        s2 = __builtin_amdgcn_mfma_f32_16x16x32_bf16(qf[3], b3, s2, 0, 0, 0);

        const int cb = nt * 2 + (li >> 3);
        const int sg = j * 64 + nt * 16 + li;
#pragma unroll
        for (int r = 0; r < 4; ++r) {
          const int row = w * 16 + lh * 4 + r;
          float p1, p2;
          if (diag && sg > t0 + row) {
            p1 = 0.f; p2 = 0.f;
          } else {
            p1 = exp2f(fmaf(s1[r], KS, -CB));
            p2 = exp2f(fmaf(s2[r], KS, -CB));
          }
          l1p[r] += p1; l2p[r] += p2;
          const int idx = row * 64 + ((cb ^ (row & 7)) << 3) + (li & 7);
          Ps1[idx] = f2bu(p1);
          Ps2[idx] = f2bu(p2);
        }
      }

      // ---- O += P @ V (A-frags from wave-private LDS rows; V from LDS) ----
#pragma unroll
      for (int kss = 0; kss < 2; ++kss) {
        const int arow = w * 16 + li;
        const int jb = ((kss * 4 + lh) ^ (li & 7)) * 8;
        bf16x8 a1f = *(const bf16x8*)&Ps1[arow * 64 + jb];
        bf16x8 a2f = *(const bf16x8*)&Ps2[arow * 64 + jb];
#pragma unroll
        for (int nt = 0; nt < 8; ++nt) {
          const int d = nt * 16 + li;
          bf16x8 vf = *(const bf16x8*)&vs[d * 64 + ((kss * 4 + lh) ^ (li & 7)) * 8];
          o1[nt] = __builtin_amdgcn_mfma_f32_16x16x32_bf16(a1f, vf, o1[nt], 0, 0, 0);
          o2[nt] = __builtin_amdgcn_mfma_f32_16x16x32_bf16(a2f, vf, o2[nt], 0, 0, 0);
        }
      }
    }

    // ---- one-shot l reduction across the 16 lanes holding each row --------
#pragma unroll
    for (int r = 0; r < 4; ++r) {
#pragma unroll
      for (int off = 1; off < 16; off <<= 1) {
        l1p[r] += __shfl_xor(l1p[r], off);
        l2p[r] += __shfl_xor(l2p[r], off);
      }
    }

    // ---- epilogue: O = O1/l1 - lam*O2/l2, bf16, layout (b, t, h*128+d) ----
#pragma unroll
    for (int r = 0; r < 4; ++r) {
      const float inv1 = 1.f / l1p[r];
      const float inv2 = lam / l2p[r];
      u16* orow = AO + (size_t)(b * 2048 + t0 + w * 16 + lh * 4 + r) * 2048 + h * 128 + li;
#pragma unroll
      for (int nt = 0; nt < 8; ++nt)
        orow[nt * 16] = f2bu(o1[nt][r] * inv1 - o2[nt][r] * inv2);
    }
  }
}

// ---------------------------------------------------------------------------
extern "C" void kernel_launch(void* const* d_in, const int* in_sizes, int n_in,
                              void* d_out, int out_size, void* d_ws, size_t ws_size,
                              hipStream_t stream) {
  const float* x   = (const float*)d_in[0];
  const float* Wq  = (const float*)d_in[1];
  const float* Wk  = (const float*)d_in[2];
  const float* Wv  = (const float*)d_in[3];
  const float* Wo  = (const float*)d_in[4];
  const float* lam = (const float*)d_in[5];
  float* out = (float*)d_out;

  const size_t MB = 1ull << 20;
  char* ws = (char*)d_ws;
  u16* qb = (u16*)d_out;            // 16 MB scratch inside d_out (rewritten at end)
  u16* kb = qb + (size_t)4096 * 2048;

  if (ws_size >= 56 * MB) {
    // ---- fused-QKV path ----
    u16* xb = (u16*)(ws);             // 16 MB: x bf16; later AO
    u16* wT = (u16*)(ws + 16 * MB);   // 24 MB: [WqT|WkT|WvT]; later WoT (8MB)
    u16* vt = (u16*)(ws + 40 * MB);   // 16 MB: V^T per head (b,h,d,t)
    u16* ao = xb;

    f32_to_bf16_k<<<8192, 256, 0, stream>>>(x, xb, 2097152);
    transpose_f32_bf16<<<dim3(64, 64), 256, 0, stream>>>(Wq, wT, 2048, 2048);
    transpose_f32_bf16<<<dim3(64, 64), 256, 0, stream>>>(Wk, wT + (size_t)4 * MB, 2048, 2048);
    transpose_f32_bf16<<<dim3(64, 64), 256, 0, stream>>>(Wv, wT + (size_t)8 * MB, 2048, 2048);
    // fused QKV, 256^2 8-phase: C=qb (K at +4096*2048), C2=vt
    gemm256_qkv<<<dim3(384), 512, 0, stream>>>(xb, wT, qb, vt, 2048);

    diff_attn<<<dim3(512), 256, 0, stream>>>(qb, kb, vt, lam, ao);

    transpose_f32_bf16<<<dim3(64, 64), 256, 0, stream>>>(Wo, wT, 2048, 2048);
    gemm_bt<1><<<dim3(32, 16), 256, 0, stream>>>(ao, wT, out, nullptr, 4096, 2048, 2048);
  } else {
    // ---- fallback: R5 sequence (40 MB scratch) ----
    u16* xb = (u16*)(ws);
    u16* wT = (u16*)(ws + 16 * MB);
    u16* vt = (u16*)(ws + 24 * MB);
    u16* ao = xb;

    f32_to_bf16_k<<<8192, 256, 0, stream>>>(x, xb, 2097152);
    transpose_f32_bf16<<<dim3(64, 64), 256, 0, stream>>>(Wq, wT, 2048, 2048);
    gemm_bt<0><<<dim3(32, 16), 256, 0, stream>>>(xb, wT, qb, nullptr, 4096, 2048, 2048);
    transpose_f32_bf16<<<dim3(64, 64), 256, 0, stream>>>(Wk, wT, 2048, 2048);
    gemm_bt<0><<<dim3(32, 16), 256, 0, stream>>>(xb, wT, kb, nullptr, 4096, 2048, 2048);
    transpose_f32_bf16<<<dim3(64, 64), 256, 0, stream>>>(Wv, wT, 2048, 2048);
    gemm_bt<2><<<dim3(32, 16), 256, 0, stream>>>(xb, wT, vt, nullptr, 4096, 2048, 2048);

    diff_attn<<<dim3(512), 256, 0, stream>>>(qb, kb, vt, lam, ao);

    transpose_f32_bf16<<<dim3(64, 64), 256, 0, stream>>>(Wo, wT, 2048, 2048);
    gemm_bt<1><<<dim3(32, 16), 256, 0, stream>>>(ao, wT, out, nullptr, 4096, 2048, 2048);
  }
}